// Round 5
// baseline (183.311 us; speedup 1.0000x reference)
//
#include <hip/hip_runtime.h>
#include <math.h>

// B=32, M=512, E=256, H=8, A=64. Rows R=B*M=16384, groups G=H*B=256, panel=32768.
// Pipeline: cast x->f16; fused W transpose-cast; fused QKV GEMM (global_load_lds +
// row&7 XOR swizzle) + R GEMM; K/V per-group transposes; flash attention with
// DIRECT-GLOBAL K/V fragment reads (no K/V LDS, no barriers, independent waves),
// swapped-QK^T wave-parallel softmax; finalize head-mean + R + relu.

typedef _Float16 f16;
typedef _Float16 f16x2 __attribute__((ext_vector_type(2)));
typedef _Float16 f16x4 __attribute__((ext_vector_type(4)));
typedef _Float16 f16x8 __attribute__((ext_vector_type(8)));
typedef float    f32x4 __attribute__((ext_vector_type(4)));

typedef __attribute__((address_space(1))) const void* gas_t;
typedef __attribute__((address_space(3))) void* las_t;

__device__ __forceinline__ void gload16(const void* g, void* l) {
  __builtin_amdgcn_global_load_lds((gas_t)g, (las_t)l, 16, 0, 0);
}

// ---------------- cast fp32 -> f16 (x4) ----------------
__global__ __launch_bounds__(256) void k_cast(const float* __restrict__ in,
                                              f16* __restrict__ out, int n4) {
  int i = blockIdx.x * 256 + threadIdx.x;
  if (i < n4) {
    f32x4 v = reinterpret_cast<const f32x4*>(in)[i];
    f16x4 h;
    h[0] = (f16)v[0]; h[1] = (f16)v[1]; h[2] = (f16)v[2]; h[3] = (f16)v[3];
    reinterpret_cast<f16x4*>(out)[i] = h;
  }
}

// ---------------- fused weight transpose-cast: Wq|Wk|Wv -> Wt[1536][256], Wr -> Wrt[64][256] ----------------
__global__ __launch_bounds__(256) void k_transpose_w(const float* __restrict__ Wq,
                                                     const float* __restrict__ Wk,
                                                     const float* __restrict__ Wv,
                                                     const float* __restrict__ Wr,
                                                     f16* __restrict__ Wt,
                                                     f16* __restrict__ Wrt) {
  __shared__ f16 tile[64][68];
  int b = blockIdx.x;
  const float* src; f16* dst; int r0, c0, Cin;
  if (b < 96) {
    int ws = b >> 5, rem = b & 31;
    src = (ws == 0) ? Wq : (ws == 1) ? Wk : Wv;
    dst = Wt + ws * 512 * 256;
    Cin = 512; r0 = (rem >> 3) * 64; c0 = (rem & 7) * 64;
  } else {
    src = Wr; dst = Wrt; Cin = 64; r0 = (b - 96) * 64; c0 = 0;
  }
  int t = threadIdx.x;
#pragma unroll
  for (int u = 0; u < 8; ++u) {
    int e = u * 256 + t;
    int r = e >> 5, c = (e & 31) << 1;
    const float* p = src + (long)(r0 + r) * Cin + (c0 + c);
    f16x2 v; v[0] = (f16)p[0]; v[1] = (f16)p[1];
    *reinterpret_cast<f16x2*>(&tile[r][c]) = v;
  }
  __syncthreads();
#pragma unroll
  for (int u = 0; u < 16; ++u) {
    int f = u * 256 + t;
    int cc = f >> 6, rr = f & 63;
    dst[(long)(c0 + cc) * 256 + (r0 + rr)] = tile[rr][cc];
  }
}

// ---------------- per-group 64x64-tile transpose (f16->f16) ----------------
__global__ __launch_bounds__(256) void k_transpose(const f16* __restrict__ in,
                                                   f16* __restrict__ out,
                                                   int R_, int C_) {
  __shared__ f16 tile[64][68];
  int g = blockIdx.x;
  long gb = (long)g * R_ * C_;
  int r0 = blockIdx.y * 64, c0 = blockIdx.z * 64;
  int t = threadIdx.x;
#pragma unroll
  for (int u = 0; u < 8; ++u) {
    int e = u * 256 + t;
    int r = e >> 5, c = (e & 31) << 1;
    const f16* p = in + gb + (long)(r0 + r) * C_ + (c0 + c);
    f16x2 v; v[0] = p[0]; v[1] = p[1];
    *reinterpret_cast<f16x2*>(&tile[r][c]) = v;
  }
  __syncthreads();
#pragma unroll
  for (int u = 0; u < 16; ++u) {
    int f = u * 256 + t;
    int cc = f >> 6, rr = f & 63;
    out[gb + (long)(c0 + cc) * R_ + (r0 + rr)] = tile[rr][cc];
  }
}

// ---------------- f16 MFMA GEMM via global_load_lds + XOR swizzle (validated R3) ----------------
template <int BN, bool F32OUT>
__global__ __launch_bounds__(256, 3) void k_gemm(const f16* __restrict__ Xh,
                                                 const f16* __restrict__ Wt,
                                                 f16* __restrict__ outH,
                                                 float* __restrict__ outF, int N) {
  __shared__ f16 Ash[128 * 64];
  __shared__ f16 Bsh[BN * 64];
  constexpr int NT = BN / 32;
  int t = threadIdx.x;
  int w = t >> 6, l = t & 63;
  int lrow = l & 15, lg = l >> 4;
  int wm = w >> 1, wn = w & 1;
  int rb = blockIdx.x * 128, cb = blockIdx.y * BN;

  f32x4 acc[4][NT] = {};

  for (int kt = 0; kt < 4; ++kt) {
    int kb = kt * 64;
    __syncthreads();
#pragma unroll
    for (int i = 0; i < 4; ++i) {
      int slot = i * 256 + t;
      int row = slot >> 3, pblk = slot & 7;
      int blk = pblk ^ (row & 7);
      gload16(Xh + (long)(rb + row) * 256 + kb + blk * 8, Ash + slot * 8);
    }
#pragma unroll
    for (int i = 0; i < BN / 32; ++i) {
      int slot = i * 256 + t;
      int row = slot >> 3, pblk = slot & 7;
      int blk = pblk ^ (row & 7);
      gload16(Wt + (long)(cb + row) * 256 + kb + blk * 8, Bsh + slot * 8);
    }
    __syncthreads();

    f16x8 af[4][2];
#pragma unroll
    for (int mi = 0; mi < 4; ++mi)
#pragma unroll
      for (int ks = 0; ks < 2; ++ks) {
        int r = 64 * wm + 16 * mi + lrow;
        af[mi][ks] = *reinterpret_cast<const f16x8*>(
            Ash + r * 64 + (((4 * ks + lg) ^ (lrow & 7)) * 8));
      }
#pragma unroll
    for (int nt = 0; nt < NT; ++nt) {
      int rB = (BN / 2) * wn + 16 * nt + lrow;
      f16x8 b0 = *reinterpret_cast<const f16x8*>(Bsh + rB * 64 + ((lg ^ (lrow & 7)) * 8));
      f16x8 b1 = *reinterpret_cast<const f16x8*>(Bsh + rB * 64 + (((4 + lg) ^ (lrow & 7)) * 8));
#pragma unroll
      for (int mi = 0; mi < 4; ++mi) {
        acc[mi][nt] = __builtin_amdgcn_mfma_f32_16x16x32_f16(af[mi][0], b0, acc[mi][nt], 0, 0, 0);
        acc[mi][nt] = __builtin_amdgcn_mfma_f32_16x16x32_f16(af[mi][1], b1, acc[mi][nt], 0, 0, 0);
      }
    }
  }
#pragma unroll
  for (int mi = 0; mi < 4; ++mi)
#pragma unroll
    for (int nt = 0; nt < NT; ++nt)
#pragma unroll
      for (int r = 0; r < 4; ++r) {
        int row = rb + 64 * wm + 16 * mi + 4 * (l >> 4) + r;
        int col = cb + (BN / 2) * wn + 16 * nt + lrow;
        float v = acc[mi][nt][r];
        if constexpr (F32OUT) {
          outF[(long)row * N + col] = v;
        } else {
          long idx = ((long)(col >> 9) << 23) + (long)row * 512 + (col & 511);
          outH[idx] = (f16)v;
        }
      }
}

// ---------------- flash attention: direct-global K/V frags, no barriers ----------------
// Qh panels [m][a]; Ktg panels [n][a]; Vtg panels [a][n]; Of f16 panels [m][a].
__global__ __launch_bounds__(256, 4) void k_attn(const f16* __restrict__ Qh,
                                                 const f16* __restrict__ Ktg,
                                                 const f16* __restrict__ Vtg,
                                                 f16* __restrict__ Of) {
  __shared__ f16 Psh[4][32][72];   // per-wave P [qrow'][key']; 2-way banks (free)
  // XCD-co-locating decode: the 4 row-blocks of a group share u&7 (same XCD slot).
  int u = blockIdx.x;
  int g = (u & 7) | ((u >> 5) << 3);
  int mb = (u >> 3) & 3;
  int t = threadIdx.x, w = t >> 6, l = t & 63;
  int lrow = l & 15, lg = l >> 4, lk8 = lg * 8;
  long gp = (long)g * 32768;
  const f16* Qg = Qh + gp;
  const f16* Kg = Ktg + gp;
  const f16* Vg = Vtg + gp;
  f16* Og = Of + gp;
  int m0 = mb * 128 + w * 32;

  // Q B-operand fragments (panel [m][a], a contiguous).
  f16x8 qf[2][2];
#pragma unroll
  for (int mi = 0; mi < 2; ++mi)
#pragma unroll
    for (int ks = 0; ks < 2; ++ks)
      qf[mi][ks] = *reinterpret_cast<const f16x8*>(Qg + (long)(m0 + 16 * mi + lrow) * 64 + 32 * ks + lk8);

  f32x4 accO[2][4] = {};
  float Mx[2] = {-INFINITY, -INFINITY}, Ls[2] = {0.f, 0.f};

  for (int c = 0; c < 8; ++c) {
    // S^T = K · Q^T. A-frag direct from Ktg: row n = c*64+16nt+lrow, k=a contiguous.
    f32x4 St[2][4] = {};
    __builtin_amdgcn_s_setprio(1);
#pragma unroll
    for (int nt = 0; nt < 4; ++nt) {
      const f16* kr = Kg + (long)(c * 64 + 16 * nt + lrow) * 64 + lk8;
      f16x8 ka = *reinterpret_cast<const f16x8*>(kr);
      f16x8 kb = *reinterpret_cast<const f16x8*>(kr + 32);
#pragma unroll
      for (int mi = 0; mi < 2; ++mi) {
        St[mi][nt] = __builtin_amdgcn_mfma_f32_16x16x32_f16(ka, qf[mi][0], St[mi][nt], 0, 0, 0);
        St[mi][nt] = __builtin_amdgcn_mfma_f32_16x16x32_f16(kb, qf[mi][1], St[mi][nt], 0, 0, 0);
      }
    }
    __builtin_amdgcn_s_setprio(0);

    // wave-parallel online softmax (lane owns qrow = 16mi+lrow; keys split across lg)
    float scb[2][4];
#pragma unroll
    for (int mi = 0; mi < 2; ++mi) {
      float tm = St[mi][0][0];
#pragma unroll
      for (int nt = 0; nt < 4; ++nt)
#pragma unroll
        for (int r = 0; r < 4; ++r) tm = fmaxf(tm, St[mi][nt][r]);
      tm = fmaxf(tm, __shfl_xor(tm, 16));
      tm = fmaxf(tm, __shfl_xor(tm, 32));
      float nm = fmaxf(Mx[mi], tm);
      float sc = __expf(Mx[mi] - nm);   // chunk 0: exp(-inf)=0
      Mx[mi] = nm;
      float ps = 0.f;
#pragma unroll
      for (int nt = 0; nt < 4; ++nt)
#pragma unroll
        for (int r = 0; r < 4; ++r) {
          float p = __expf(St[mi][nt][r] - nm);
          St[mi][nt][r] = p;
          ps += p;
        }
      ps += __shfl_xor(ps, 16);
      ps += __shfl_xor(ps, 32);
      Ls[mi] = Ls[mi] * sc + ps;
#pragma unroll
      for (int nt = 0; nt < 4; ++nt) {
        f16x4 p4;
        p4[0] = (f16)St[mi][nt][0]; p4[1] = (f16)St[mi][nt][1];
        p4[2] = (f16)St[mi][nt][2]; p4[3] = (f16)St[mi][nt][3];
        *reinterpret_cast<f16x4*>(&Psh[w][16 * mi + lrow][16 * nt + 4 * lg]) = p4;
      }
#pragma unroll
      for (int r = 0; r < 4; ++r) scb[mi][r] = __shfl(sc, 20 * lg + r);
    }
#pragma unroll
    for (int mi = 0; mi < 2; ++mi)
#pragma unroll
      for (int at = 0; at < 4; ++at)
#pragma unroll
        for (int r = 0; r < 4; ++r) accO[mi][at][r] *= scb[mi][r];

    // O += P · V. A-frag = own wave's Psh (no barrier); B-frag direct from Vtg:
    // row a = 16at+lrow, key = c*64 + 32ks + lk8 contiguous.
    __builtin_amdgcn_s_setprio(1);
#pragma unroll
    for (int ks = 0; ks < 2; ++ks) {
      f16x8 pa[2];
#pragma unroll
      for (int mi = 0; mi < 2; ++mi)
        pa[mi] = *reinterpret_cast<const f16x8*>(&Psh[w][16 * mi + lrow][32 * ks + lk8]);
#pragma unroll
      for (int at = 0; at < 4; ++at) {
        f16x8 vb = *reinterpret_cast<const f16x8*>(
            Vg + (long)(16 * at + lrow) * 512 + c * 64 + 32 * ks + lk8);
#pragma unroll
        for (int mi = 0; mi < 2; ++mi)
          accO[mi][at] = __builtin_amdgcn_mfma_f32_16x16x32_f16(pa[mi], vb, accO[mi][at], 0, 0, 0);
      }
    }
    __builtin_amdgcn_s_setprio(0);
  }

  // epilogue: redistribute 1/L, normalize, store f16
#pragma unroll
  for (int mi = 0; mi < 2; ++mi) {
    float inv = 1.f / Ls[mi];
    float invb[4];
#pragma unroll
    for (int r = 0; r < 4; ++r) invb[r] = __shfl(inv, 20 * lg + r);
#pragma unroll
    for (int r = 0; r < 4; ++r) {
      int row = m0 + 16 * mi + 4 * lg + r;
#pragma unroll
      for (int at = 0; at < 4; ++at)
        Og[(long)row * 64 + 16 * at + lrow] = (f16)(accO[mi][at][r] * invb[r]);
    }
  }
}

// ---------------- finalize: head-mean + R + relu ----------------
__global__ __launch_bounds__(256) void k_finalize(const f16* __restrict__ Of,
                                                  const float* __restrict__ Rf,
                                                  float* __restrict__ out) {
  int i = blockIdx.x * 256 + threadIdx.x;
  f32x4 s = {};
#pragma unroll
  for (int h = 0; h < 8; ++h) {
    f16x4 o = reinterpret_cast<const f16x4*>(Of + (long)h * 1048576)[i];
#pragma unroll
    for (int j = 0; j < 4; ++j) s[j] += (float)o[j];
  }
  f32x4 r = reinterpret_cast<const f32x4*>(Rf)[i];
  f32x4 v = s * 0.125f + r;
#pragma unroll
  for (int j = 0; j < 4; ++j) v[j] = v[j] > 0.f ? v[j] : 0.f;
  reinterpret_cast<f32x4*>(out)[i] = v;
}

extern "C" void kernel_launch(void* const* d_in, const int* in_sizes, int n_in,
                              void* d_out, int out_size, void* d_ws, size_t ws_size,
                              hipStream_t stream) {
  const float* x  = (const float*)d_in[0];
  const float* Wq = (const float*)d_in[1];
  const float* Wk = (const float*)d_in[2];
  const float* Wv = (const float*)d_in[3];
  const float* Wr = (const float*)d_in[4];
  float* out = (float*)d_out;
  char* w = (char*)d_ws;

  // workspace layout (bytes), ~92.8 MiB total:
  f16*   Xh   = (f16*)(w + 0);           // 8,388,608
  f16*   Wt   = (f16*)(w + 8388608);     // 786,432
  f16*   Wrt  = (f16*)(w + 9175040);     // 32,768
  f16*   QKV  = (f16*)(w + 9207808);     // Qh|Kn|Vn, 3 x 16,777,216 (2^23 elems apart)
  f16*   Qh   = QKV;
  f16*   Kn   = (f16*)(w + 25985024);
  f16*   Vn   = (f16*)(w + 42762240);
  f16*   Ktg  = (f16*)(w + 59539456);    // 16,777,216
  f16*   Vtg  = (f16*)(w + 76316672);    // 16,777,216
  float* Rf   = (float*)(w + 93093888);  // 4,194,304
  f16*   Of   = (f16*)(w + 25985024);    // overlay over Kn (dead after transposes)

  k_cast<<<4096, 256, 0, stream>>>(x, Xh, 1048576);
  k_transpose_w<<<100, 256, 0, stream>>>(Wq, Wk, Wv, Wr, Wt, Wrt);

  k_gemm<128, false><<<dim3(128, 12), 256, 0, stream>>>(Xh, Wt, QKV, nullptr, 512);
  k_gemm<64, true><<<dim3(128, 1), 256, 0, stream>>>(Xh, Wrt, nullptr, Rf, 64);

  // K panels (64x512)->[n][a]; V panels (512x64)->[a][n]
  k_transpose<<<dim3(256, 1, 8), 256, 0, stream>>>(Kn, Ktg, 64, 512);
  k_transpose<<<dim3(256, 8, 1), 256, 0, stream>>>(Vn, Vtg, 512, 64);

  k_attn<<<1024, 256, 0, stream>>>(Qh, Ktg, Vtg, Of);
  k_finalize<<<1024, 256, 0, stream>>>(Of, Rf, out);
}

// Round 8
// 148.793 us; speedup vs baseline: 1.2320x; 1.2320x over previous
//
#include <hip/hip_runtime.h>
#include <math.h>

// B=32, M=512, E=256, H=8, A=64. Rows R=B*M=16384, groups G=H*B=256, panel=32768.
// Pipeline: cast x->f16; fused W transpose-cast; fused QKV GEMM (global_load_lds +
// row&7 XOR swizzle) + R GEMM; K/V per-group transposes; flash attention with
// DOUBLE-BUFFERED async K/V staging (global_load_lds, counted vmcnt, raw s_barrier),
// swapped-QK^T wave-parallel softmax; finalize head-mean + R + relu.

typedef _Float16 f16;
typedef _Float16 f16x2 __attribute__((ext_vector_type(2)));
typedef _Float16 f16x4 __attribute__((ext_vector_type(4)));
typedef _Float16 f16x8 __attribute__((ext_vector_type(8)));
typedef float    f32x4 __attribute__((ext_vector_type(4)));

typedef __attribute__((address_space(1))) const void* gas_t;
typedef __attribute__((address_space(3))) void* las_t;

__device__ __forceinline__ void gload16(const void* g, void* l) {
  __builtin_amdgcn_global_load_lds((gas_t)g, (las_t)l, 16, 0, 0);
}

// ---------------- cast fp32 -> f16 (x4) ----------------
__global__ __launch_bounds__(256) void k_cast(const float* __restrict__ in,
                                              f16* __restrict__ out, int n4) {
  int i = blockIdx.x * 256 + threadIdx.x;
  if (i < n4) {
    f32x4 v = reinterpret_cast<const f32x4*>(in)[i];
    f16x4 h;
    h[0] = (f16)v[0]; h[1] = (f16)v[1]; h[2] = (f16)v[2]; h[3] = (f16)v[3];
    reinterpret_cast<f16x4*>(out)[i] = h;
  }
}

// ---------------- fused weight transpose-cast: Wq|Wk|Wv -> Wt[1536][256], Wr -> Wrt[64][256] ----------------
__global__ __launch_bounds__(256) void k_transpose_w(const float* __restrict__ Wq,
                                                     const float* __restrict__ Wk,
                                                     const float* __restrict__ Wv,
                                                     const float* __restrict__ Wr,
                                                     f16* __restrict__ Wt,
                                                     f16* __restrict__ Wrt) {
  __shared__ f16 tile[64][68];
  int b = blockIdx.x;
  const float* src; f16* dst; int r0, c0, Cin;
  if (b < 96) {
    int ws = b >> 5, rem = b & 31;
    src = (ws == 0) ? Wq : (ws == 1) ? Wk : Wv;
    dst = Wt + ws * 512 * 256;
    Cin = 512; r0 = (rem >> 3) * 64; c0 = (rem & 7) * 64;
  } else {
    src = Wr; dst = Wrt; Cin = 64; r0 = (b - 96) * 64; c0 = 0;
  }
  int t = threadIdx.x;
#pragma unroll
  for (int u = 0; u < 8; ++u) {
    int e = u * 256 + t;
    int r = e >> 5, c = (e & 31) << 1;
    const float* p = src + (long)(r0 + r) * Cin + (c0 + c);
    f16x2 v; v[0] = (f16)p[0]; v[1] = (f16)p[1];
    *reinterpret_cast<f16x2*>(&tile[r][c]) = v;
  }
  __syncthreads();
#pragma unroll
  for (int u = 0; u < 16; ++u) {
    int f = u * 256 + t;
    int cc = f >> 6, rr = f & 63;
    dst[(long)(c0 + cc) * 256 + (r0 + rr)] = tile[rr][cc];
  }
}

// ---------------- per-group 64x64-tile transpose (f16->f16) ----------------
__global__ __launch_bounds__(256) void k_transpose(const f16* __restrict__ in,
                                                   f16* __restrict__ out,
                                                   int R_, int C_) {
  __shared__ f16 tile[64][68];
  int g = blockIdx.x;
  long gb = (long)g * R_ * C_;
  int r0 = blockIdx.y * 64, c0 = blockIdx.z * 64;
  int t = threadIdx.x;
#pragma unroll
  for (int u = 0; u < 8; ++u) {
    int e = u * 256 + t;
    int r = e >> 5, c = (e & 31) << 1;
    const f16* p = in + gb + (long)(r0 + r) * C_ + (c0 + c);
    f16x2 v; v[0] = p[0]; v[1] = p[1];
    *reinterpret_cast<f16x2*>(&tile[r][c]) = v;
  }
  __syncthreads();
#pragma unroll
  for (int u = 0; u < 16; ++u) {
    int f = u * 256 + t;
    int cc = f >> 6, rr = f & 63;
    out[gb + (long)(c0 + cc) * R_ + (r0 + rr)] = tile[rr][cc];
  }
}

// ---------------- f16 MFMA GEMM via global_load_lds + XOR swizzle (validated R3) ----------------
template <int BN, bool F32OUT>
__global__ __launch_bounds__(256, 3) void k_gemm(const f16* __restrict__ Xh,
                                                 const f16* __restrict__ Wt,
                                                 f16* __restrict__ outH,
                                                 float* __restrict__ outF, int N) {
  __shared__ f16 Ash[128 * 64];
  __shared__ f16 Bsh[BN * 64];
  constexpr int NT = BN / 32;
  int t = threadIdx.x;
  int w = t >> 6, l = t & 63;
  int lrow = l & 15, lg = l >> 4;
  int wm = w >> 1, wn = w & 1;
  int rb = blockIdx.x * 128, cb = blockIdx.y * BN;

  f32x4 acc[4][NT] = {};

  for (int kt = 0; kt < 4; ++kt) {
    int kb = kt * 64;
    __syncthreads();
#pragma unroll
    for (int i = 0; i < 4; ++i) {
      int slot = i * 256 + t;
      int row = slot >> 3, pblk = slot & 7;
      int blk = pblk ^ (row & 7);
      gload16(Xh + (long)(rb + row) * 256 + kb + blk * 8, Ash + slot * 8);
    }
#pragma unroll
    for (int i = 0; i < BN / 32; ++i) {
      int slot = i * 256 + t;
      int row = slot >> 3, pblk = slot & 7;
      int blk = pblk ^ (row & 7);
      gload16(Wt + (long)(cb + row) * 256 + kb + blk * 8, Bsh + slot * 8);
    }
    __syncthreads();

    f16x8 af[4][2];
#pragma unroll
    for (int mi = 0; mi < 4; ++mi)
#pragma unroll
      for (int ks = 0; ks < 2; ++ks) {
        int r = 64 * wm + 16 * mi + lrow;
        af[mi][ks] = *reinterpret_cast<const f16x8*>(
            Ash + r * 64 + (((4 * ks + lg) ^ (lrow & 7)) * 8));
      }
#pragma unroll
    for (int nt = 0; nt < NT; ++nt) {
      int rB = (BN / 2) * wn + 16 * nt + lrow;
      f16x8 b0 = *reinterpret_cast<const f16x8*>(Bsh + rB * 64 + ((lg ^ (lrow & 7)) * 8));
      f16x8 b1 = *reinterpret_cast<const f16x8*>(Bsh + rB * 64 + (((4 + lg) ^ (lrow & 7)) * 8));
#pragma unroll
      for (int mi = 0; mi < 4; ++mi) {
        acc[mi][nt] = __builtin_amdgcn_mfma_f32_16x16x32_f16(af[mi][0], b0, acc[mi][nt], 0, 0, 0);
        acc[mi][nt] = __builtin_amdgcn_mfma_f32_16x16x32_f16(af[mi][1], b1, acc[mi][nt], 0, 0, 0);
      }
    }
  }
#pragma unroll
  for (int mi = 0; mi < 4; ++mi)
#pragma unroll
    for (int nt = 0; nt < NT; ++nt)
#pragma unroll
      for (int r = 0; r < 4; ++r) {
        int row = rb + 64 * wm + 16 * mi + 4 * (l >> 4) + r;
        int col = cb + (BN / 2) * wn + 16 * nt + lrow;
        float v = acc[mi][nt][r];
        if constexpr (F32OUT) {
          outF[(long)row * N + col] = v;
        } else {
          long idx = ((long)(col >> 9) << 23) + (long)row * 512 + (col & 511);
          outH[idx] = (f16)v;
        }
      }
}

// ---------------- flash attention: double-buffered async K/V staging ----------------
// Qh panels [m][a]; Ktg panels [n][a]; Vtg panels [a][n]; Of f16 panels [m][a].
// LDS tiles are [64 rows][8 x 16B blocks], physical block = logical ^ (row&7);
// DMA dest linear (uniform base + lane*16), global source pre-swizzled (rule 21).
__global__ __launch_bounds__(256, 3) void k_attn(const f16* __restrict__ Qh,
                                                 const f16* __restrict__ Ktg,
                                                 const f16* __restrict__ Vtg,
                                                 f16* __restrict__ Of) {
  __shared__ f16 Ksh[2][64 * 64];
  __shared__ f16 Vsh[2][64 * 64];
  __shared__ f16 Psh[4][32][72];
  int u = blockIdx.x;
  int g = (u & 7) | ((u >> 5) << 3);   // 4 row-blocks of a group share u&7 (same XCD slot)
  int mb = (u >> 3) & 3;
  int t = threadIdx.x, w = t >> 6, l = t & 63;
  int lrow = l & 15, lg = l >> 4, lk8 = lg * 8;
  long gp = (long)g * 32768;
  const f16* Qg = Qh + gp;
  const f16* Kg = Ktg + gp;
  const f16* Vg = Vtg + gp;
  f16* Og = Of + gp;
  int m0 = mb * 128 + w * 32;

  // Q B-operand fragments (panel [m][a], a contiguous).
  f16x8 qf[2][2];
#pragma unroll
  for (int mi = 0; mi < 2; ++mi)
#pragma unroll
    for (int ks = 0; ks < 2; ++ks)
      qf[mi][ks] = *reinterpret_cast<const f16x8*>(Qg + (long)(m0 + 16 * mi + lrow) * 64 + 32 * ks + lk8);

  // stage chunk c into buffer buf: 2 K-DMA + 2 V-DMA per thread (16B each).
  auto stage = [&](int buf, int c) {
#pragma unroll
    for (int s = 0; s < 2; ++s) {
      int slot = s * 256 + t;
      int row = slot >> 3, pblk = slot & 7;
      gload16(Kg + (long)c * 4096 + row * 64 + ((pblk ^ (row & 7)) * 8),
              Ksh[buf] + slot * 8);
    }
#pragma unroll
    for (int s = 0; s < 2; ++s) {
      int slot = s * 256 + t;
      int a = slot >> 3, pblk = slot & 7;
      gload16(Vg + (long)a * 512 + c * 64 + ((pblk ^ (a & 7)) * 8),
              Vsh[buf] + slot * 8);
    }
  };

  f32x4 accO[2][4] = {};
  float Mx[2] = {-INFINITY, -INFINITY}, Ls[2] = {0.f, 0.f};

  stage(0, 0);
  stage(1, 1);

  for (int c = 0; c < 8; ++c) {
    int buf = c & 1;
    // wait own prefetch for chunk c (keep chunk c+1's 4 loads in flight), then
    // raw barrier so ALL waves' DMA for chunk c has landed.
    if (c < 7) asm volatile("s_waitcnt vmcnt(4)" ::: "memory");
    else       asm volatile("s_waitcnt vmcnt(0)" ::: "memory");
    __builtin_amdgcn_s_barrier();

    // S^T = K · Q^T : A-frag from Ksh (swizzled b128, 2-way max).
    f32x4 St[2][4] = {};
    __builtin_amdgcn_s_setprio(1);
#pragma unroll
    for (int nt = 0; nt < 4; ++nt) {
      int n = 16 * nt + lrow, nb = n & 7;
      f16x8 ka = *reinterpret_cast<const f16x8*>(Ksh[buf] + n * 64 + ((lg ^ nb) * 8));
      f16x8 kb = *reinterpret_cast<const f16x8*>(Ksh[buf] + n * 64 + (((4 + lg) ^ nb) * 8));
#pragma unroll
      for (int mi = 0; mi < 2; ++mi) {
        St[mi][nt] = __builtin_amdgcn_mfma_f32_16x16x32_f16(ka, qf[mi][0], St[mi][nt], 0, 0, 0);
        St[mi][nt] = __builtin_amdgcn_mfma_f32_16x16x32_f16(kb, qf[mi][1], St[mi][nt], 0, 0, 0);
      }
    }
    __builtin_amdgcn_s_setprio(0);

    // wave-parallel online softmax (lane owns qrow = 16mi+lrow; keys split across lg)
    float scb[2][4];
#pragma unroll
    for (int mi = 0; mi < 2; ++mi) {
      float tm = St[mi][0][0];
#pragma unroll
      for (int nt = 0; nt < 4; ++nt)
#pragma unroll
        for (int r = 0; r < 4; ++r) tm = fmaxf(tm, St[mi][nt][r]);
      tm = fmaxf(tm, __shfl_xor(tm, 16));
      tm = fmaxf(tm, __shfl_xor(tm, 32));
      float nm = fmaxf(Mx[mi], tm);
      float sc = __expf(Mx[mi] - nm);   // chunk 0: exp(-inf)=0
      Mx[mi] = nm;
      float ps = 0.f;
#pragma unroll
      for (int nt = 0; nt < 4; ++nt)
#pragma unroll
        for (int r = 0; r < 4; ++r) {
          float p = __expf(St[mi][nt][r] - nm);
          St[mi][nt][r] = p;
          ps += p;
        }
      ps += __shfl_xor(ps, 16);
      ps += __shfl_xor(ps, 32);
      Ls[mi] = Ls[mi] * sc + ps;
#pragma unroll
      for (int nt = 0; nt < 4; ++nt) {
        f16x4 p4;
        p4[0] = (f16)St[mi][nt][0]; p4[1] = (f16)St[mi][nt][1];
        p4[2] = (f16)St[mi][nt][2]; p4[3] = (f16)St[mi][nt][3];
        *reinterpret_cast<f16x4*>(&Psh[w][16 * mi + lrow][16 * nt + 4 * lg]) = p4;
      }
#pragma unroll
      for (int r = 0; r < 4; ++r) scb[mi][r] = __shfl(sc, 20 * lg + r);
    }
#pragma unroll
    for (int mi = 0; mi < 2; ++mi)
#pragma unroll
      for (int at = 0; at < 4; ++at)
#pragma unroll
        for (int r = 0; r < 4; ++r) accO[mi][at][r] *= scb[mi][r];

    // O += P · V. A-frag = own wave's Psh; B-frag from Vsh (swizzled b128, 2-way max).
    __builtin_amdgcn_s_setprio(1);
#pragma unroll
    for (int ks = 0; ks < 2; ++ks) {
      f16x8 pa[2];
#pragma unroll
      for (int mi = 0; mi < 2; ++mi)
        pa[mi] = *reinterpret_cast<const f16x8*>(&Psh[w][16 * mi + lrow][32 * ks + lk8]);
#pragma unroll
      for (int at = 0; at < 4; ++at) {
        int a = 16 * at + lrow, ab = a & 7;
        f16x8 vb = *reinterpret_cast<const f16x8*>(Vsh[buf] + a * 64 + (((4 * ks + lg) ^ ab) * 8));
#pragma unroll
        for (int mi = 0; mi < 2; ++mi)
          accO[mi][at] = __builtin_amdgcn_mfma_f32_16x16x32_f16(pa[mi], vb, accO[mi][at], 0, 0, 0);
      }
    }
    __builtin_amdgcn_s_setprio(0);

    // all waves done reading buf -> safe to overwrite with chunk c+2's DMA
    __builtin_amdgcn_s_barrier();
    if (c + 2 < 8) stage(buf, c + 2);
  }

  // epilogue: redistribute 1/L, normalize, store f16
#pragma unroll
  for (int mi = 0; mi < 2; ++mi) {
    float inv = 1.f / Ls[mi];
    float invb[4];
#pragma unroll
    for (int r = 0; r < 4; ++r) invb[r] = __shfl(inv, 20 * lg + r);
#pragma unroll
    for (int r = 0; r < 4; ++r) {
      int row = m0 + 16 * mi + 4 * lg + r;
#pragma unroll
      for (int at = 0; at < 4; ++at)
        Og[(long)row * 64 + 16 * at + lrow] = (f16)(accO[mi][at][r] * invb[r]);
    }
  }
}

// ---------------- finalize: head-mean + R + relu ----------------
__global__ __launch_bounds__(256) void k_finalize(const f16* __restrict__ Of,
                                                  const float* __restrict__ Rf,
                                                  float* __restrict__ out) {
  int i = blockIdx.x * 256 + threadIdx.x;
  f32x4 s = {};
#pragma unroll
  for (int h = 0; h < 8; ++h) {
    f16x4 o = reinterpret_cast<const f16x4*>(Of + (long)h * 1048576)[i];
#pragma unroll
    for (int j = 0; j < 4; ++j) s[j] += (float)o[j];
  }
  f32x4 r = reinterpret_cast<const f32x4*>(Rf)[i];
  f32x4 v = s * 0.125f + r;
#pragma unroll
  for (int j = 0; j < 4; ++j) v[j] = v[j] > 0.f ? v[j] : 0.f;
  reinterpret_cast<f32x4*>(out)[i] = v;
}

extern "C" void kernel_launch(void* const* d_in, const int* in_sizes, int n_in,
                              void* d_out, int out_size, void* d_ws, size_t ws_size,
                              hipStream_t stream) {
  const float* x  = (const float*)d_in[0];
  const float* Wq = (const float*)d_in[1];
  const float* Wk = (const float*)d_in[2];
  const float* Wv = (const float*)d_in[3];
  const float* Wr = (const float*)d_in[4];
  float* out = (float*)d_out;
  char* w = (char*)d_ws;

  // workspace layout (bytes), ~92.8 MiB total:
  f16*   Xh   = (f16*)(w + 0);           // 8,388,608
  f16*   Wt   = (f16*)(w + 8388608);     // 786,432
  f16*   Wrt  = (f16*)(w + 9175040);     // 32,768
  f16*   QKV  = (f16*)(w + 9207808);     // Qh|Kn|Vn, 3 x 16,777,216 (2^23 elems apart)
  f16*   Qh   = QKV;
  f16*   Kn   = (f16*)(w + 25985024);
  f16*   Vn   = (f16*)(w + 42762240);
  f16*   Ktg  = (f16*)(w + 59539456);    // 16,777,216
  f16*   Vtg  = (f16*)(w + 76316672);    // 16,777,216
  float* Rf   = (float*)(w + 93093888);  // 4,194,304
  f16*   Of   = (f16*)(w + 25985024);    // overlay over Kn (dead after transposes)

  k_cast<<<4096, 256, 0, stream>>>(x, Xh, 1048576);
  k_transpose_w<<<100, 256, 0, stream>>>(Wq, Wk, Wv, Wr, Wt, Wrt);

  k_gemm<128, false><<<dim3(128, 12), 256, 0, stream>>>(Xh, Wt, QKV, nullptr, 512);
  k_gemm<64, true><<<dim3(128, 1), 256, 0, stream>>>(Xh, Wrt, nullptr, Rf, 64);

  // K panels (64x512)->[n][a]; V panels (512x64)->[a][n]
  k_transpose<<<dim3(256, 1, 8), 256, 0, stream>>>(Kn, Ktg, 64, 512);
  k_transpose<<<dim3(256, 8, 1), 256, 0, stream>>>(Vn, Vtg, 512, 64);

  k_attn<<<1024, 256, 0, stream>>>(Qh, Ktg, Vtg, Of);
  k_finalize<<<1024, 256, 0, stream>>>(Of, Rf, out);
}

// Round 9
// 139.805 us; speedup vs baseline: 1.3112x; 1.0643x over previous
//
#include <hip/hip_runtime.h>
#include <math.h>

// B=32, M=512, E=256, H=8, A=64. Rows R=B*M=16384, groups G=H*B=256, panel=32768.
// Pipeline: cast x->f16; fused W transpose-cast; fused QKV GEMM that writes
// Q natural, K as Ktg[i][a], V as Vtg[a][i] (key-permuted i = ((n&7)<<6)|(n>>3),
// transposed through LDS in the epilogue) + R GEMM; flash attention (unchanged,
// double-buffered async K/V staging); finalize head-mean + R + relu.

typedef _Float16 f16;
typedef _Float16 f16x2 __attribute__((ext_vector_type(2)));
typedef _Float16 f16x4 __attribute__((ext_vector_type(4)));
typedef _Float16 f16x8 __attribute__((ext_vector_type(8)));
typedef float    f32x4 __attribute__((ext_vector_type(4)));

typedef __attribute__((address_space(1))) const void* gas_t;
typedef __attribute__((address_space(3))) void* las_t;

__device__ __forceinline__ void gload16(const void* g, void* l) {
  __builtin_amdgcn_global_load_lds((gas_t)g, (las_t)l, 16, 0, 0);
}

// ---------------- cast fp32 -> f16 (x4) ----------------
__global__ __launch_bounds__(256) void k_cast(const float* __restrict__ in,
                                              f16* __restrict__ out, int n4) {
  int i = blockIdx.x * 256 + threadIdx.x;
  if (i < n4) {
    f32x4 v = reinterpret_cast<const f32x4*>(in)[i];
    f16x4 h;
    h[0] = (f16)v[0]; h[1] = (f16)v[1]; h[2] = (f16)v[2]; h[3] = (f16)v[3];
    reinterpret_cast<f16x4*>(out)[i] = h;
  }
}

// ---------------- fused weight transpose-cast: Wq|Wk|Wv -> Wt[1536][256], Wr -> Wrt[64][256] ----------------
__global__ __launch_bounds__(256) void k_transpose_w(const float* __restrict__ Wq,
                                                     const float* __restrict__ Wk,
                                                     const float* __restrict__ Wv,
                                                     const float* __restrict__ Wr,
                                                     f16* __restrict__ Wt,
                                                     f16* __restrict__ Wrt) {
  __shared__ f16 tile[64][68];
  int b = blockIdx.x;
  const float* src; f16* dst; int r0, c0, Cin;
  if (b < 96) {
    int ws = b >> 5, rem = b & 31;
    src = (ws == 0) ? Wq : (ws == 1) ? Wk : Wv;
    dst = Wt + ws * 512 * 256;
    Cin = 512; r0 = (rem >> 3) * 64; c0 = (rem & 7) * 64;
  } else {
    src = Wr; dst = Wrt; Cin = 64; r0 = (b - 96) * 64; c0 = 0;
  }
  int t = threadIdx.x;
#pragma unroll
  for (int u = 0; u < 8; ++u) {
    int e = u * 256 + t;
    int r = e >> 5, c = (e & 31) << 1;
    const float* p = src + (long)(r0 + r) * Cin + (c0 + c);
    f16x2 v; v[0] = (f16)p[0]; v[1] = (f16)p[1];
    *reinterpret_cast<f16x2*>(&tile[r][c]) = v;
  }
  __syncthreads();
#pragma unroll
  for (int u = 0; u < 16; ++u) {
    int f = u * 256 + t;
    int cc = f >> 6, rr = f & 63;
    dst[(long)(c0 + cc) * 256 + (r0 + rr)] = tile[rr][cc];
  }
}

// ---------------- f16 MFMA GEMM + fused transposed K/V epilogues ----------------
// C(16384 x N) = Xh(16384x256) @ Wt ([col][k]). For !F32OUT (QKV, grid y 0..11):
//   third 0 (Q): natural panel writes to outH.
//   third 1 (K): LDS-retile -> Ktg[i][a] at outH + 2^23, i = ((n&7)<<6)|(n>>3).
//   third 2 (V): LDS-retile -> Vtg[a][i] at outH + 2^24 (block covers i-range
//                [128j,128j+128) contiguously under the same permutation).
template <int BN, bool F32OUT>
__global__ __launch_bounds__(256, 3) void k_gemm(const f16* __restrict__ Xh,
                                                 const f16* __restrict__ Wt,
                                                 f16* __restrict__ outH,
                                                 float* __restrict__ outF, int N) {
  __shared__ f16 smem[18432];           // Ash(8192) | Bsh(<=8192); reused as epilogue tile
  f16* Ash = smem;
  f16* Bsh = smem + 8192;
  constexpr int NT = BN / 32;
  int t = threadIdx.x;
  int w = t >> 6, l = t & 63;
  int lrow = l & 15, lg = l >> 4;
  int wm = w >> 1, wn = w & 1;
  int rb = blockIdx.x * 128, cb = blockIdx.y * BN;

  f32x4 acc[4][NT] = {};

  for (int kt = 0; kt < 4; ++kt) {
    int kb = kt * 64;
    __syncthreads();
#pragma unroll
    for (int i = 0; i < 4; ++i) {
      int slot = i * 256 + t;
      int row = slot >> 3, pblk = slot & 7;
      int blk = pblk ^ (row & 7);
      gload16(Xh + (long)(rb + row) * 256 + kb + blk * 8, Ash + slot * 8);
    }
#pragma unroll
    for (int i = 0; i < BN / 32; ++i) {
      int slot = i * 256 + t;
      int row = slot >> 3, pblk = slot & 7;
      int blk = pblk ^ (row & 7);
      gload16(Wt + (long)(cb + row) * 256 + kb + blk * 8, Bsh + slot * 8);
    }
    __syncthreads();

    f16x8 af[4][2];
#pragma unroll
    for (int mi = 0; mi < 4; ++mi)
#pragma unroll
      for (int ks = 0; ks < 2; ++ks) {
        int r = 64 * wm + 16 * mi + lrow;
        af[mi][ks] = *reinterpret_cast<const f16x8*>(
            Ash + r * 64 + (((4 * ks + lg) ^ (lrow & 7)) * 8));
      }
#pragma unroll
    for (int nt = 0; nt < NT; ++nt) {
      int rB = (BN / 2) * wn + 16 * nt + lrow;
      f16x8 b0 = *reinterpret_cast<const f16x8*>(Bsh + rB * 64 + ((lg ^ (lrow & 7)) * 8));
      f16x8 b1 = *reinterpret_cast<const f16x8*>(Bsh + rB * 64 + (((4 + lg) ^ (lrow & 7)) * 8));
#pragma unroll
      for (int mi = 0; mi < 4; ++mi) {
        acc[mi][nt] = __builtin_amdgcn_mfma_f32_16x16x32_f16(af[mi][0], b0, acc[mi][nt], 0, 0, 0);
        acc[mi][nt] = __builtin_amdgcn_mfma_f32_16x16x32_f16(af[mi][1], b1, acc[mi][nt], 0, 0, 0);
      }
    }
  }

  if constexpr (F32OUT) {
#pragma unroll
    for (int mi = 0; mi < 4; ++mi)
#pragma unroll
      for (int nt = 0; nt < NT; ++nt)
#pragma unroll
        for (int r = 0; r < 4; ++r) {
          int row = rb + 64 * wm + 16 * mi + 4 * lg + r;
          int col = cb + (BN / 2) * wn + 16 * nt + lrow;
          outF[(long)row * N + col] = acc[mi][nt][r];
        }
  } else {
    int third = blockIdx.y >> 2;
    if (third == 0) {                    // Q: natural panel layout
#pragma unroll
      for (int mi = 0; mi < 4; ++mi)
#pragma unroll
        for (int nt = 0; nt < NT; ++nt)
#pragma unroll
          for (int r = 0; r < 4; ++r) {
            int row = rb + 64 * wm + 16 * mi + 4 * lg + r;
            int col = cb + 64 * wn + 16 * nt + lrow;
            outH[(long)row * 512 + col] = (f16)acc[mi][nt][r];
          }
    } else if (third == 1) {             // K -> Ktg[i][a], via LDS retile
      int cbK = cb - 512;
      __syncthreads();                   // Ash/Bsh dead; reuse smem as tile
#pragma unroll
      for (int mi = 0; mi < 4; ++mi)
#pragma unroll
        for (int nt = 0; nt < NT; ++nt)
#pragma unroll
          for (int r = 0; r < 4; ++r) {
            int nl = 64 * wn + 16 * nt + lrow;      // n - cbK, [0,128)
            int a  = 16 * mi + 4 * lg + r;          // row&63
            smem[wm * 9216 + nl * 72 + a] = (f16)acc[mi][nt][r];
          }
      __syncthreads();
      f16* Kt = outH + (1 << 23);
#pragma unroll
      for (int u = 0; u < 8; ++u) {
        int sid = u * 256 + t;
        int wmt = sid >> 10, rem = sid & 1023;
        int nl = rem >> 3, a8 = rem & 7;
        int g = (rb >> 6) + wmt;
        int n = cbK + nl;
        int i = ((n & 7) << 6) | (n >> 3);
        *reinterpret_cast<f16x8*>(Kt + (long)g * 32768 + i * 64 + a8 * 8) =
            *reinterpret_cast<const f16x8*>(smem + wmt * 9216 + nl * 72 + a8 * 8);
      }
    } else {                             // V -> Vtg[a][i], via LDS retile
      int j = blockIdx.y - 8;
      __syncthreads();
#pragma unroll
      for (int mi = 0; mi < 4; ++mi)
#pragma unroll
        for (int nt = 0; nt < NT; ++nt)
#pragma unroll
          for (int r = 0; r < 4; ++r) {
            int a   = 16 * nt + lrow;               // cv&63
            int npl = 64 * wn + 16 * mi + 4 * lg + r;  // i - 128j, [0,128)
            smem[wm * 8704 + a * 136 + npl] = (f16)acc[mi][nt][r];
          }
      __syncthreads();
      f16* Vt = outH + (2 << 23);
#pragma unroll
      for (int u = 0; u < 8; ++u) {
        int sid = u * 256 + t;
        int wmt = sid >> 10, rem = sid & 1023;
        int a = rem >> 4, n8 = rem & 15;
        int g = (rb >> 6) + wmt;
        *reinterpret_cast<f16x8*>(Vt + (long)g * 32768 + a * 512 + j * 128 + n8 * 8) =
            *reinterpret_cast<const f16x8*>(smem + wmt * 8704 + a * 136 + n8 * 8);
      }
    }
  }
}

// ---------------- flash attention: double-buffered async K/V staging (unchanged R8) ----------------
__global__ __launch_bounds__(256, 3) void k_attn(const f16* __restrict__ Qh,
                                                 const f16* __restrict__ Ktg,
                                                 const f16* __restrict__ Vtg,
                                                 f16* __restrict__ Of) {
  __shared__ f16 Ksh[2][64 * 64];
  __shared__ f16 Vsh[2][64 * 64];
  __shared__ f16 Psh[4][32][72];
  int u = blockIdx.x;
  int g = (u & 7) | ((u >> 5) << 3);
  int mb = (u >> 3) & 3;
  int t = threadIdx.x, w = t >> 6, l = t & 63;
  int lrow = l & 15, lg = l >> 4, lk8 = lg * 8;
  long gp = (long)g * 32768;
  const f16* Qg = Qh + gp;
  const f16* Kg = Ktg + gp;
  const f16* Vg = Vtg + gp;
  f16* Og = Of + gp;
  int m0 = mb * 128 + w * 32;

  f16x8 qf[2][2];
#pragma unroll
  for (int mi = 0; mi < 2; ++mi)
#pragma unroll
    for (int ks = 0; ks < 2; ++ks)
      qf[mi][ks] = *reinterpret_cast<const f16x8*>(Qg + (long)(m0 + 16 * mi + lrow) * 64 + 32 * ks + lk8);

  auto stage = [&](int buf, int c) {
#pragma unroll
    for (int s = 0; s < 2; ++s) {
      int slot = s * 256 + t;
      int row = slot >> 3, pblk = slot & 7;
      gload16(Kg + (long)c * 4096 + row * 64 + ((pblk ^ (row & 7)) * 8),
              Ksh[buf] + slot * 8);
    }
#pragma unroll
    for (int s = 0; s < 2; ++s) {
      int slot = s * 256 + t;
      int a = slot >> 3, pblk = slot & 7;
      gload16(Vg + (long)a * 512 + c * 64 + ((pblk ^ (a & 7)) * 8),
              Vsh[buf] + slot * 8);
    }
  };

  f32x4 accO[2][4] = {};
  float Mx[2] = {-INFINITY, -INFINITY}, Ls[2] = {0.f, 0.f};

  stage(0, 0);
  stage(1, 1);

  for (int c = 0; c < 8; ++c) {
    int buf = c & 1;
    if (c < 7) asm volatile("s_waitcnt vmcnt(4)" ::: "memory");
    else       asm volatile("s_waitcnt vmcnt(0)" ::: "memory");
    __builtin_amdgcn_s_barrier();

    f32x4 St[2][4] = {};
    __builtin_amdgcn_s_setprio(1);
#pragma unroll
    for (int nt = 0; nt < 4; ++nt) {
      int n = 16 * nt + lrow, nb = n & 7;
      f16x8 ka = *reinterpret_cast<const f16x8*>(Ksh[buf] + n * 64 + ((lg ^ nb) * 8));
      f16x8 kb = *reinterpret_cast<const f16x8*>(Ksh[buf] + n * 64 + (((4 + lg) ^ nb) * 8));
#pragma unroll
      for (int mi = 0; mi < 2; ++mi) {
        St[mi][nt] = __builtin_amdgcn_mfma_f32_16x16x32_f16(ka, qf[mi][0], St[mi][nt], 0, 0, 0);
        St[mi][nt] = __builtin_amdgcn_mfma_f32_16x16x32_f16(kb, qf[mi][1], St[mi][nt], 0, 0, 0);
      }
    }
    __builtin_amdgcn_s_setprio(0);

    float scb[2][4];
#pragma unroll
    for (int mi = 0; mi < 2; ++mi) {
      float tm = St[mi][0][0];
#pragma unroll
      for (int nt = 0; nt < 4; ++nt)
#pragma unroll
        for (int r = 0; r < 4; ++r) tm = fmaxf(tm, St[mi][nt][r]);
      tm = fmaxf(tm, __shfl_xor(tm, 16));
      tm = fmaxf(tm, __shfl_xor(tm, 32));
      float nm = fmaxf(Mx[mi], tm);
      float sc = __expf(Mx[mi] - nm);
      Mx[mi] = nm;
      float ps = 0.f;
#pragma unroll
      for (int nt = 0; nt < 4; ++nt)
#pragma unroll
        for (int r = 0; r < 4; ++r) {
          float p = __expf(St[mi][nt][r] - nm);
          St[mi][nt][r] = p;
          ps += p;
        }
      ps += __shfl_xor(ps, 16);
      ps += __shfl_xor(ps, 32);
      Ls[mi] = Ls[mi] * sc + ps;
#pragma unroll
      for (int nt = 0; nt < 4; ++nt) {
        f16x4 p4;
        p4[0] = (f16)St[mi][nt][0]; p4[1] = (f16)St[mi][nt][1];
        p4[2] = (f16)St[mi][nt][2]; p4[3] = (f16)St[mi][nt][3];
        *reinterpret_cast<f16x4*>(&Psh[w][16 * mi + lrow][16 * nt + 4 * lg]) = p4;
      }
#pragma unroll
      for (int r = 0; r < 4; ++r) scb[mi][r] = __shfl(sc, 20 * lg + r);
    }
#pragma unroll
    for (int mi = 0; mi < 2; ++mi)
#pragma unroll
      for (int at = 0; at < 4; ++at)
#pragma unroll
        for (int r = 0; r < 4; ++r) accO[mi][at][r] *= scb[mi][r];

    __builtin_amdgcn_s_setprio(1);
#pragma unroll
    for (int ks = 0; ks < 2; ++ks) {
      f16x8 pa[2];
#pragma unroll
      for (int mi = 0; mi < 2; ++mi)
        pa[mi] = *reinterpret_cast<const f16x8*>(&Psh[w][16 * mi + lrow][32 * ks + lk8]);
#pragma unroll
      for (int at = 0; at < 4; ++at) {
        int a = 16 * at + lrow, ab = a & 7;
        f16x8 vb = *reinterpret_cast<const f16x8*>(Vsh[buf] + a * 64 + (((4 * ks + lg) ^ ab) * 8));
#pragma unroll
        for (int mi = 0; mi < 2; ++mi)
          accO[mi][at] = __builtin_amdgcn_mfma_f32_16x16x32_f16(pa[mi], vb, accO[mi][at], 0, 0, 0);
      }
    }
    __builtin_amdgcn_s_setprio(0);

    __builtin_amdgcn_s_barrier();
    if (c + 2 < 8) stage(buf, c + 2);
  }

#pragma unroll
  for (int mi = 0; mi < 2; ++mi) {
    float inv = 1.f / Ls[mi];
    float invb[4];
#pragma unroll
    for (int r = 0; r < 4; ++r) invb[r] = __shfl(inv, 20 * lg + r);
#pragma unroll
    for (int r = 0; r < 4; ++r) {
      int row = m0 + 16 * mi + 4 * lg + r;
#pragma unroll
      for (int at = 0; at < 4; ++at)
        Og[(long)row * 64 + 16 * at + lrow] = (f16)(accO[mi][at][r] * invb[r]);
    }
  }
}

// ---------------- finalize: head-mean + R + relu ----------------
__global__ __launch_bounds__(256) void k_finalize(const f16* __restrict__ Of,
                                                  const float* __restrict__ Rf,
                                                  float* __restrict__ out) {
  int i = blockIdx.x * 256 + threadIdx.x;
  f32x4 s = {};
#pragma unroll
  for (int h = 0; h < 8; ++h) {
    f16x4 o = reinterpret_cast<const f16x4*>(Of + (long)h * 1048576)[i];
#pragma unroll
    for (int j = 0; j < 4; ++j) s[j] += (float)o[j];
  }
  f32x4 r = reinterpret_cast<const f32x4*>(Rf)[i];
  f32x4 v = s * 0.125f + r;
#pragma unroll
  for (int j = 0; j < 4; ++j) v[j] = v[j] > 0.f ? v[j] : 0.f;
  reinterpret_cast<f32x4*>(out)[i] = v;
}

extern "C" void kernel_launch(void* const* d_in, const int* in_sizes, int n_in,
                              void* d_out, int out_size, void* d_ws, size_t ws_size,
                              hipStream_t stream) {
  const float* x  = (const float*)d_in[0];
  const float* Wq = (const float*)d_in[1];
  const float* Wk = (const float*)d_in[2];
  const float* Wv = (const float*)d_in[3];
  const float* Wr = (const float*)d_in[4];
  float* out = (float*)d_out;
  char* w = (char*)d_ws;

  // workspace layout (bytes), ~80.5 MiB total:
  f16*   Xh   = (f16*)(w + 0);           // 8,388,608
  f16*   Wt   = (f16*)(w + 8388608);     // 786,432
  f16*   Wrt  = (f16*)(w + 9175040);     // 32,768
  f16*   Qh   = (f16*)(w + 9207808);     // Q|Ktg|Vtg contiguous, 3 x 16,777,216 (2^23 f16 apart)
  f16*   Ktg  = (f16*)(w + 25985024);
  f16*   Vtg  = (f16*)(w + 42762240);
  float* Rf   = (float*)(w + 59539456);  // 4,194,304
  f16*   Of   = (f16*)(w + 63733760);    // 16,777,216

  k_cast<<<4096, 256, 0, stream>>>(x, Xh, 1048576);
  k_transpose_w<<<100, 256, 0, stream>>>(Wq, Wk, Wv, Wr, Wt, Wrt);

  k_gemm<128, false><<<dim3(128, 12), 256, 0, stream>>>(Xh, Wt, Qh, nullptr, 512);
  k_gemm<64, true><<<dim3(128, 1), 256, 0, stream>>>(Xh, Wrt, nullptr, Rf, 64);

  k_attn<<<1024, 256, 0, stream>>>(Qh, Ktg, Vtg, Of);
  k_finalize<<<1024, 256, 0, stream>>>(Of, Rf, out);
}

// Round 12
// 136.882 us; speedup vs baseline: 1.3392x; 1.0214x over previous
//
#include <hip/hip_runtime.h>
#include <math.h>

// B=32, M=512, E=256, H=8, A=64. Rows R=B*M=16384, groups G=H*B=256, panel=32768.
// Pipeline: cast x->f16; fused W transpose-cast; fused QKV GEMM that writes
// Q natural, K as Ktg[i][a], V as Vtg[a][i] (key-permuted, transposed through LDS
// in the epilogue) + R GEMM; flash attention with double-buffered async K/V staging,
// kappa-relabeled K rows so the PV A-fragment is lane-local (NO Psh LDS roundtrip);
// finalize head-mean + R + relu.

typedef _Float16 f16;
typedef _Float16 f16x2 __attribute__((ext_vector_type(2)));
typedef _Float16 f16x4 __attribute__((ext_vector_type(4)));
typedef _Float16 f16x8 __attribute__((ext_vector_type(8)));
typedef float    f32x4 __attribute__((ext_vector_type(4)));

typedef __attribute__((address_space(1))) const void* gas_t;
typedef __attribute__((address_space(3))) void* las_t;

__device__ __forceinline__ void gload16(const void* g, void* l) {
  __builtin_amdgcn_global_load_lds((gas_t)g, (las_t)l, 16, 0, 0);
}

// ---------------- cast fp32 -> f16 (x4) ----------------
__global__ __launch_bounds__(256) void k_cast(const float* __restrict__ in,
                                              f16* __restrict__ out, int n4) {
  int i = blockIdx.x * 256 + threadIdx.x;
  if (i < n4) {
    f32x4 v = reinterpret_cast<const f32x4*>(in)[i];
    f16x4 h;
    h[0] = (f16)v[0]; h[1] = (f16)v[1]; h[2] = (f16)v[2]; h[3] = (f16)v[3];
    reinterpret_cast<f16x4*>(out)[i] = h;
  }
}

// ---------------- fused weight transpose-cast: Wq|Wk|Wv -> Wt[1536][256], Wr -> Wrt[64][256] ----------------
__global__ __launch_bounds__(256) void k_transpose_w(const float* __restrict__ Wq,
                                                     const float* __restrict__ Wk,
                                                     const float* __restrict__ Wv,
                                                     const float* __restrict__ Wr,
                                                     f16* __restrict__ Wt,
                                                     f16* __restrict__ Wrt) {
  __shared__ f16 tile[64][68];
  int b = blockIdx.x;
  const float* src; f16* dst; int r0, c0, Cin;
  if (b < 96) {
    int ws = b >> 5, rem = b & 31;
    src = (ws == 0) ? Wq : (ws == 1) ? Wk : Wv;
    dst = Wt + ws * 512 * 256;
    Cin = 512; r0 = (rem >> 3) * 64; c0 = (rem & 7) * 64;
  } else {
    src = Wr; dst = Wrt; Cin = 64; r0 = (b - 96) * 64; c0 = 0;
  }
  int t = threadIdx.x;
#pragma unroll
  for (int u = 0; u < 8; ++u) {
    int e = u * 256 + t;
    int r = e >> 5, c = (e & 31) << 1;
    const float* p = src + (long)(r0 + r) * Cin + (c0 + c);
    f16x2 v; v[0] = (f16)p[0]; v[1] = (f16)p[1];
    *reinterpret_cast<f16x2*>(&tile[r][c]) = v;
  }
  __syncthreads();
#pragma unroll
  for (int u = 0; u < 16; ++u) {
    int f = u * 256 + t;
    int cc = f >> 6, rr = f & 63;
    dst[(long)(c0 + cc) * 256 + (r0 + rr)] = tile[rr][cc];
  }
}

// ---------------- f16 MFMA GEMM + fused transposed K/V epilogues (validated R9) ----------------
template <int BN, bool F32OUT>
__global__ __launch_bounds__(256, 3) void k_gemm(const f16* __restrict__ Xh,
                                                 const f16* __restrict__ Wt,
                                                 f16* __restrict__ outH,
                                                 float* __restrict__ outF, int N) {
  __shared__ f16 smem[18432];           // Ash(8192) | Bsh(<=8192); reused as epilogue tile
  f16* Ash = smem;
  f16* Bsh = smem + 8192;
  constexpr int NT = BN / 32;
  int t = threadIdx.x;
  int w = t >> 6, l = t & 63;
  int lrow = l & 15, lg = l >> 4;
  int wm = w >> 1, wn = w & 1;
  int rb = blockIdx.x * 128, cb = blockIdx.y * BN;

  f32x4 acc[4][NT] = {};

  for (int kt = 0; kt < 4; ++kt) {
    int kb = kt * 64;
    __syncthreads();
#pragma unroll
    for (int i = 0; i < 4; ++i) {
      int slot = i * 256 + t;
      int row = slot >> 3, pblk = slot & 7;
      int blk = pblk ^ (row & 7);
      gload16(Xh + (long)(rb + row) * 256 + kb + blk * 8, Ash + slot * 8);
    }
#pragma unroll
    for (int i = 0; i < BN / 32; ++i) {
      int slot = i * 256 + t;
      int row = slot >> 3, pblk = slot & 7;
      int blk = pblk ^ (row & 7);
      gload16(Wt + (long)(cb + row) * 256 + kb + blk * 8, Bsh + slot * 8);
    }
    __syncthreads();

    f16x8 af[4][2];
#pragma unroll
    for (int mi = 0; mi < 4; ++mi)
#pragma unroll
      for (int ks = 0; ks < 2; ++ks) {
        int r = 64 * wm + 16 * mi + lrow;
        af[mi][ks] = *reinterpret_cast<const f16x8*>(
            Ash + r * 64 + (((4 * ks + lg) ^ (lrow & 7)) * 8));
      }
#pragma unroll
    for (int nt = 0; nt < NT; ++nt) {
      int rB = (BN / 2) * wn + 16 * nt + lrow;
      f16x8 b0 = *reinterpret_cast<const f16x8*>(Bsh + rB * 64 + ((lg ^ (lrow & 7)) * 8));
      f16x8 b1 = *reinterpret_cast<const f16x8*>(Bsh + rB * 64 + (((4 + lg) ^ (lrow & 7)) * 8));
#pragma unroll
      for (int mi = 0; mi < 4; ++mi) {
        acc[mi][nt] = __builtin_amdgcn_mfma_f32_16x16x32_f16(af[mi][0], b0, acc[mi][nt], 0, 0, 0);
        acc[mi][nt] = __builtin_amdgcn_mfma_f32_16x16x32_f16(af[mi][1], b1, acc[mi][nt], 0, 0, 0);
      }
    }
  }

  if constexpr (F32OUT) {
#pragma unroll
    for (int mi = 0; mi < 4; ++mi)
#pragma unroll
      for (int nt = 0; nt < NT; ++nt)
#pragma unroll
        for (int r = 0; r < 4; ++r) {
          int row = rb + 64 * wm + 16 * mi + 4 * lg + r;
          int col = cb + (BN / 2) * wn + 16 * nt + lrow;
          outF[(long)row * N + col] = acc[mi][nt][r];
        }
  } else {
    int third = blockIdx.y >> 2;
    if (third == 0) {                    // Q: natural panel layout
#pragma unroll
      for (int mi = 0; mi < 4; ++mi)
#pragma unroll
        for (int nt = 0; nt < NT; ++nt)
#pragma unroll
          for (int r = 0; r < 4; ++r) {
            int row = rb + 64 * wm + 16 * mi + 4 * lg + r;
            int col = cb + 64 * wn + 16 * nt + lrow;
            outH[(long)row * 512 + col] = (f16)acc[mi][nt][r];
          }
    } else if (third == 1) {             // K -> Ktg[i][a], via LDS retile
      int cbK = cb - 512;
      __syncthreads();
#pragma unroll
      for (int mi = 0; mi < 4; ++mi)
#pragma unroll
        for (int nt = 0; nt < NT; ++nt)
#pragma unroll
          for (int r = 0; r < 4; ++r) {
            int nl = 64 * wn + 16 * nt + lrow;
            int a  = 16 * mi + 4 * lg + r;
            smem[wm * 9216 + nl * 72 + a] = (f16)acc[mi][nt][r];
          }
      __syncthreads();
      f16* Kt = outH + (1 << 23);
#pragma unroll
      for (int u = 0; u < 8; ++u) {
        int sid = u * 256 + t;
        int wmt = sid >> 10, rem = sid & 1023;
        int nl = rem >> 3, a8 = rem & 7;
        int g = (rb >> 6) + wmt;
        int n = cbK + nl;
        int i = ((n & 7) << 6) | (n >> 3);
        *reinterpret_cast<f16x8*>(Kt + (long)g * 32768 + i * 64 + a8 * 8) =
            *reinterpret_cast<const f16x8*>(smem + wmt * 9216 + nl * 72 + a8 * 8);
      }
    } else {                             // V -> Vtg[a][i], via LDS retile
      int j = blockIdx.y - 8;
      __syncthreads();
#pragma unroll
      for (int mi = 0; mi < 4; ++mi)
#pragma unroll
        for (int nt = 0; nt < NT; ++nt)
#pragma unroll
          for (int r = 0; r < 4; ++r) {
            int a   = 16 * nt + lrow;
            int npl = 64 * wn + 16 * mi + 4 * lg + r;
            smem[wm * 8704 + a * 136 + npl] = (f16)acc[mi][nt][r];
          }
      __syncthreads();
      f16* Vt = outH + (2 << 23);
#pragma unroll
      for (int u = 0; u < 8; ++u) {
        int sid = u * 256 + t;
        int wmt = sid >> 10, rem = sid & 1023;
        int a = rem >> 4, n8 = rem & 15;
        int g = (rb >> 6) + wmt;
        *reinterpret_cast<f16x8*>(Vt + (long)g * 32768 + a * 512 + j * 128 + n8 * 8) =
            *reinterpret_cast<const f16x8*>(smem + wmt * 8704 + a * 136 + n8 * 8);
      }
    }
  }
}

// ---------------- flash attention: dbuf async K/V staging, kappa-relabeled K, no Psh ----------------
// K LDS row p holds global key kappa(p) = 32(p>>5) + 8((p>>2)&3) + 4((p>>4)&1) + (p&3),
// so the swapped-QK^T output St[mi][nt][r] packs DIRECTLY into the PV A-fragment:
// pa[mi][ks] = {St[mi][2ks][0..3], St[mi][2ks+1][0..3]} holds keys 32ks+8lg+j in order.
// V staging stays identity (B-frag position == key). Softmax is key-order-invariant.
__global__ __launch_bounds__(256, 4) void k_attn(const f16* __restrict__ Qh,
                                                 const f16* __restrict__ Ktg,
                                                 const f16* __restrict__ Vtg,
                                                 f16* __restrict__ Of) {
  __shared__ f16 Ksh[2][64 * 64];
  __shared__ f16 Vsh[2][64 * 64];
  int u = blockIdx.x;
  int g = (u & 7) | ((u >> 5) << 3);   // 4 row-blocks of a group share u&7 (same XCD slot)
  int mb = (u >> 3) & 3;
  int t = threadIdx.x, w = t >> 6, l = t & 63;
  int lrow = l & 15, lg = l >> 4, lk8 = lg * 8;
  long gp = (long)g * 32768;
  const f16* Qg = Qh + gp;
  const f16* Kg = Ktg + gp;
  const f16* Vg = Vtg + gp;
  f16* Og = Of + gp;
  int m0 = mb * 128 + w * 32;

  f16x8 qf[2][2];
#pragma unroll
  for (int mi = 0; mi < 2; ++mi)
#pragma unroll
    for (int ks = 0; ks < 2; ++ks)
      qf[mi][ks] = *reinterpret_cast<const f16x8*>(Qg + (long)(m0 + 16 * mi + lrow) * 64 + 32 * ks + lk8);

  // stage chunk c: K row p <- global key kappa(p) (pre-swizzled src, linear dest);
  // V identity. 2 K-DMA + 2 V-DMA per thread (16B each).
  auto stage = [&](int buf, int c) {
#pragma unroll
    for (int s = 0; s < 2; ++s) {
      int slot = s * 256 + t;
      int row = slot >> 3, pblk = slot & 7;
      int kr = 32 * (row >> 5) + 8 * ((row >> 2) & 3) + 4 * ((row >> 4) & 1) + (row & 3);
      gload16(Kg + (long)c * 4096 + kr * 64 + ((pblk ^ (row & 7)) * 8),
              Ksh[buf] + slot * 8);
    }
#pragma unroll
    for (int s = 0; s < 2; ++s) {
      int slot = s * 256 + t;
      int a = slot >> 3, pblk = slot & 7;
      gload16(Vg + (long)a * 512 + c * 64 + ((pblk ^ (a & 7)) * 8),
              Vsh[buf] + slot * 8);
    }
  };

  f32x4 accO[2][4] = {};
  float Mx[2] = {-INFINITY, -INFINITY}, Ls[2] = {0.f, 0.f};

  stage(0, 0);
  stage(1, 1);

  for (int c = 0; c < 8; ++c) {
    int buf = c & 1;
    if (c < 7) asm volatile("s_waitcnt vmcnt(4)" ::: "memory");
    else       asm volatile("s_waitcnt vmcnt(0)" ::: "memory");
    __builtin_amdgcn_s_barrier();

    // S^T = K . Q^T : A-frag from Ksh (swizzled b128, 2-way max).
    f32x4 St[2][4] = {};
    __builtin_amdgcn_s_setprio(1);
#pragma unroll
    for (int nt = 0; nt < 4; ++nt) {
      int n = 16 * nt + lrow, nb = n & 7;
      f16x8 ka = *reinterpret_cast<const f16x8*>(Ksh[buf] + n * 64 + ((lg ^ nb) * 8));
      f16x8 kb = *reinterpret_cast<const f16x8*>(Ksh[buf] + n * 64 + (((4 + lg) ^ nb) * 8));
#pragma unroll
      for (int mi = 0; mi < 2; ++mi) {
        St[mi][nt] = __builtin_amdgcn_mfma_f32_16x16x32_f16(ka, qf[mi][0], St[mi][nt], 0, 0, 0);
        St[mi][nt] = __builtin_amdgcn_mfma_f32_16x16x32_f16(kb, qf[mi][1], St[mi][nt], 0, 0, 0);
      }
    }
    __builtin_amdgcn_s_setprio(0);

    // wave-parallel online softmax (lane owns qrow = 16mi+lrow; keys split across lg)
    float scb[2][4];
#pragma unroll
    for (int mi = 0; mi < 2; ++mi) {
      float tm = St[mi][0][0];
#pragma unroll
      for (int nt = 0; nt < 4; ++nt)
#pragma unroll
        for (int r = 0; r < 4; ++r) tm = fmaxf(tm, St[mi][nt][r]);
      tm = fmaxf(tm, __shfl_xor(tm, 16));
      tm = fmaxf(tm, __shfl_xor(tm, 32));
      float nm = fmaxf(Mx[mi], tm);
      float sc = __expf(Mx[mi] - nm);   // chunk 0: exp(-inf)=0
      Mx[mi] = nm;
      float ps = 0.f;
#pragma unroll
      for (int nt = 0; nt < 4; ++nt)
#pragma unroll
        for (int r = 0; r < 4; ++r) {
          float p = __expf(St[mi][nt][r] - nm);
          St[mi][nt][r] = p;
          ps += p;
        }
      ps += __shfl_xor(ps, 16);
      ps += __shfl_xor(ps, 32);
      Ls[mi] = Ls[mi] * sc + ps;
#pragma unroll
      for (int r = 0; r < 4; ++r) scb[mi][r] = __shfl(sc, 20 * lg + r);
    }
#pragma unroll
    for (int mi = 0; mi < 2; ++mi)
#pragma unroll
      for (int at = 0; at < 4; ++at)
#pragma unroll
        for (int r = 0; r < 4; ++r) accO[mi][at][r] *= scb[mi][r];

    // O += P . V : A-frag packed IN-REGISTER from St (kappa makes it lane-local);
    // B-frag from Vsh (swizzled b128, 2-way max).
    __builtin_amdgcn_s_setprio(1);
#pragma unroll
    for (int ks = 0; ks < 2; ++ks) {
      f16x8 pa[2];
#pragma unroll
      for (int mi = 0; mi < 2; ++mi) {
        pa[mi][0] = (f16)St[mi][2 * ks][0];
        pa[mi][1] = (f16)St[mi][2 * ks][1];
        pa[mi][2] = (f16)St[mi][2 * ks][2];
        pa[mi][3] = (f16)St[mi][2 * ks][3];
        pa[mi][4] = (f16)St[mi][2 * ks + 1][0];
        pa[mi][5] = (f16)St[mi][2 * ks + 1][1];
        pa[mi][6] = (f16)St[mi][2 * ks + 1][2];
        pa[mi][7] = (f16)St[mi][2 * ks + 1][3];
      }
#pragma unroll
      for (int at = 0; at < 4; ++at) {
        int a = 16 * at + lrow, ab = a & 7;
        f16x8 vb = *reinterpret_cast<const f16x8*>(Vsh[buf] + a * 64 + (((4 * ks + lg) ^ ab) * 8));
#pragma unroll
        for (int mi = 0; mi < 2; ++mi)
          accO[mi][at] = __builtin_amdgcn_mfma_f32_16x16x32_f16(pa[mi], vb, accO[mi][at], 0, 0, 0);
      }
    }
    __builtin_amdgcn_s_setprio(0);

    __builtin_amdgcn_s_barrier();
    if (c + 2 < 8) stage(buf, c + 2);
  }

  // epilogue: redistribute 1/L, normalize, store f16
#pragma unroll
  for (int mi = 0; mi < 2; ++mi) {
    float inv = 1.f / Ls[mi];
    float invb[4];
#pragma unroll
    for (int r = 0; r < 4; ++r) invb[r] = __shfl(inv, 20 * lg + r);
#pragma unroll
    for (int r = 0; r < 4; ++r) {
      int row = m0 + 16 * mi + 4 * lg + r;
#pragma unroll
      for (int at = 0; at < 4; ++at)
        Og[(long)row * 64 + 16 * at + lrow] = (f16)(accO[mi][at][r] * invb[r]);
    }
  }
}

// ---------------- finalize: head-mean + R + relu ----------------
__global__ __launch_bounds__(256) void k_finalize(const f16* __restrict__ Of,
                                                  const float* __restrict__ Rf,
                                                  float* __restrict__ out) {
  int i = blockIdx.x * 256 + threadIdx.x;
  f32x4 s = {};
#pragma unroll
  for (int h = 0; h < 8; ++h) {
    f16x4 o = reinterpret_cast<const f16x4*>(Of + (long)h * 1048576)[i];
#pragma unroll
    for (int j = 0; j < 4; ++j) s[j] += (float)o[j];
  }
  f32x4 r = reinterpret_cast<const f32x4*>(Rf)[i];
  f32x4 v = s * 0.125f + r;
#pragma unroll
  for (int j = 0; j < 4; ++j) v[j] = v[j] > 0.f ? v[j] : 0.f;
  reinterpret_cast<f32x4*>(out)[i] = v;
}

extern "C" void kernel_launch(void* const* d_in, const int* in_sizes, int n_in,
                              void* d_out, int out_size, void* d_ws, size_t ws_size,
                              hipStream_t stream) {
  const float* x  = (const float*)d_in[0];
  const float* Wq = (const float*)d_in[1];
  const float* Wk = (const float*)d_in[2];
  const float* Wv = (const float*)d_in[3];
  const float* Wr = (const float*)d_in[4];
  float* out = (float*)d_out;
  char* w = (char*)d_ws;

  // workspace layout (bytes), ~80.5 MiB total:
  f16*   Xh   = (f16*)(w + 0);           // 8,388,608
  f16*   Wt   = (f16*)(w + 8388608);     // 786,432
  f16*   Wrt  = (f16*)(w + 9175040);     // 32,768
  f16*   Qh   = (f16*)(w + 9207808);     // Q|Ktg|Vtg contiguous, 3 x 16,777,216 (2^23 f16 apart)
  f16*   Ktg  = (f16*)(w + 25985024);
  f16*   Vtg  = (f16*)(w + 42762240);
  float* Rf   = (float*)(w + 59539456);  // 4,194,304
  f16*   Of   = (f16*)(w + 63733760);    // 16,777,216

  k_cast<<<4096, 256, 0, stream>>>(x, Xh, 1048576);
  k_transpose_w<<<100, 256, 0, stream>>>(Wq, Wk, Wv, Wr, Wt, Wrt);

  k_gemm<128, false><<<dim3(128, 12), 256, 0, stream>>>(Xh, Wt, Qh, nullptr, 512);
  k_gemm<64, true><<<dim3(128, 1), 256, 0, stream>>>(Xh, Wrt, nullptr, Rf, 64);

  k_attn<<<1024, 256, 0, stream>>>(Qh, Ktg, Vtg, Of);
  k_finalize<<<1024, 256, 0, stream>>>(Of, Rf, out);
}

// Round 13
// 130.332 us; speedup vs baseline: 1.4065x; 1.0503x over previous
//
#include <hip/hip_runtime.h>
#include <math.h>

// B=32, M=512, E=256, H=8, A=64. Rows R=B*M=16384, groups G=H*B=256, panel=32768.
// Pipeline: cast x->f16; fused W transpose-cast; fused QKV GEMM that writes
// Q natural, K as Ktg[i][a], V as Vtg[a][i] (key-permuted, transposed through LDS
// in the epilogue) + R GEMM; flash attention (QBLK=256/block, 2 blocks/group,
// double-buffered async K/V staging, kappa-relabeled K, in-register PV A-frag);
// finalize head-mean + R + relu.

typedef _Float16 f16;
typedef _Float16 f16x2 __attribute__((ext_vector_type(2)));
typedef _Float16 f16x4 __attribute__((ext_vector_type(4)));
typedef _Float16 f16x8 __attribute__((ext_vector_type(8)));
typedef float    f32x4 __attribute__((ext_vector_type(4)));

typedef __attribute__((address_space(1))) const void* gas_t;
typedef __attribute__((address_space(3))) void* las_t;

__device__ __forceinline__ void gload16(const void* g, void* l) {
  __builtin_amdgcn_global_load_lds((gas_t)g, (las_t)l, 16, 0, 0);
}

// ---------------- cast fp32 -> f16 (x4) ----------------
__global__ __launch_bounds__(256) void k_cast(const float* __restrict__ in,
                                              f16* __restrict__ out, int n4) {
  int i = blockIdx.x * 256 + threadIdx.x;
  if (i < n4) {
    f32x4 v = reinterpret_cast<const f32x4*>(in)[i];
    f16x4 h;
    h[0] = (f16)v[0]; h[1] = (f16)v[1]; h[2] = (f16)v[2]; h[3] = (f16)v[3];
    reinterpret_cast<f16x4*>(out)[i] = h;
  }
}

// ---------------- fused weight transpose-cast: Wq|Wk|Wv -> Wt[1536][256], Wr -> Wrt[64][256] ----------------
__global__ __launch_bounds__(256) void k_transpose_w(const float* __restrict__ Wq,
                                                     const float* __restrict__ Wk,
                                                     const float* __restrict__ Wv,
                                                     const float* __restrict__ Wr,
                                                     f16* __restrict__ Wt,
                                                     f16* __restrict__ Wrt) {
  __shared__ f16 tile[64][68];
  int b = blockIdx.x;
  const float* src; f16* dst; int r0, c0, Cin;
  if (b < 96) {
    int ws = b >> 5, rem = b & 31;
    src = (ws == 0) ? Wq : (ws == 1) ? Wk : Wv;
    dst = Wt + ws * 512 * 256;
    Cin = 512; r0 = (rem >> 3) * 64; c0 = (rem & 7) * 64;
  } else {
    src = Wr; dst = Wrt; Cin = 64; r0 = (b - 96) * 64; c0 = 0;
  }
  int t = threadIdx.x;
#pragma unroll
  for (int u = 0; u < 8; ++u) {
    int e = u * 256 + t;
    int r = e >> 5, c = (e & 31) << 1;
    const float* p = src + (long)(r0 + r) * Cin + (c0 + c);
    f16x2 v; v[0] = (f16)p[0]; v[1] = (f16)p[1];
    *reinterpret_cast<f16x2*>(&tile[r][c]) = v;
  }
  __syncthreads();
#pragma unroll
  for (int u = 0; u < 16; ++u) {
    int f = u * 256 + t;
    int cc = f >> 6, rr = f & 63;
    dst[(long)(c0 + cc) * 256 + (r0 + rr)] = tile[rr][cc];
  }
}

// ---------------- f16 MFMA GEMM + fused transposed K/V epilogues (validated R9) ----------------
template <int BN, bool F32OUT>
__global__ __launch_bounds__(256, 3) void k_gemm(const f16* __restrict__ Xh,
                                                 const f16* __restrict__ Wt,
                                                 f16* __restrict__ outH,
                                                 float* __restrict__ outF, int N) {
  __shared__ f16 smem[18432];           // Ash(8192) | Bsh(<=8192); reused as epilogue tile
  f16* Ash = smem;
  f16* Bsh = smem + 8192;
  constexpr int NT = BN / 32;
  int t = threadIdx.x;
  int w = t >> 6, l = t & 63;
  int lrow = l & 15, lg = l >> 4;
  int wm = w >> 1, wn = w & 1;
  int rb = blockIdx.x * 128, cb = blockIdx.y * BN;

  f32x4 acc[4][NT] = {};

  for (int kt = 0; kt < 4; ++kt) {
    int kb = kt * 64;
    __syncthreads();
#pragma unroll
    for (int i = 0; i < 4; ++i) {
      int slot = i * 256 + t;
      int row = slot >> 3, pblk = slot & 7;
      int blk = pblk ^ (row & 7);
      gload16(Xh + (long)(rb + row) * 256 + kb + blk * 8, Ash + slot * 8);
    }
#pragma unroll
    for (int i = 0; i < BN / 32; ++i) {
      int slot = i * 256 + t;
      int row = slot >> 3, pblk = slot & 7;
      int blk = pblk ^ (row & 7);
      gload16(Wt + (long)(cb + row) * 256 + kb + blk * 8, Bsh + slot * 8);
    }
    __syncthreads();

    f16x8 af[4][2];
#pragma unroll
    for (int mi = 0; mi < 4; ++mi)
#pragma unroll
      for (int ks = 0; ks < 2; ++ks) {
        int r = 64 * wm + 16 * mi + lrow;
        af[mi][ks] = *reinterpret_cast<const f16x8*>(
            Ash + r * 64 + (((4 * ks + lg) ^ (lrow & 7)) * 8));
      }
#pragma unroll
    for (int nt = 0; nt < NT; ++nt) {
      int rB = (BN / 2) * wn + 16 * nt + lrow;
      f16x8 b0 = *reinterpret_cast<const f16x8*>(Bsh + rB * 64 + ((lg ^ (lrow & 7)) * 8));
      f16x8 b1 = *reinterpret_cast<const f16x8*>(Bsh + rB * 64 + (((4 + lg) ^ (lrow & 7)) * 8));
#pragma unroll
      for (int mi = 0; mi < 4; ++mi) {
        acc[mi][nt] = __builtin_amdgcn_mfma_f32_16x16x32_f16(af[mi][0], b0, acc[mi][nt], 0, 0, 0);
        acc[mi][nt] = __builtin_amdgcn_mfma_f32_16x16x32_f16(af[mi][1], b1, acc[mi][nt], 0, 0, 0);
      }
    }
  }

  if constexpr (F32OUT) {
#pragma unroll
    for (int mi = 0; mi < 4; ++mi)
#pragma unroll
      for (int nt = 0; nt < NT; ++nt)
#pragma unroll
        for (int r = 0; r < 4; ++r) {
          int row = rb + 64 * wm + 16 * mi + 4 * lg + r;
          int col = cb + (BN / 2) * wn + 16 * nt + lrow;
          outF[(long)row * N + col] = acc[mi][nt][r];
        }
  } else {
    int third = blockIdx.y >> 2;
    if (third == 0) {                    // Q: natural panel layout
#pragma unroll
      for (int mi = 0; mi < 4; ++mi)
#pragma unroll
        for (int nt = 0; nt < NT; ++nt)
#pragma unroll
          for (int r = 0; r < 4; ++r) {
            int row = rb + 64 * wm + 16 * mi + 4 * lg + r;
            int col = cb + 64 * wn + 16 * nt + lrow;
            outH[(long)row * 512 + col] = (f16)acc[mi][nt][r];
          }
    } else if (third == 1) {             // K -> Ktg[i][a], via LDS retile
      int cbK = cb - 512;
      __syncthreads();
#pragma unroll
      for (int mi = 0; mi < 4; ++mi)
#pragma unroll
        for (int nt = 0; nt < NT; ++nt)
#pragma unroll
          for (int r = 0; r < 4; ++r) {
            int nl = 64 * wn + 16 * nt + lrow;
            int a  = 16 * mi + 4 * lg + r;
            smem[wm * 9216 + nl * 72 + a] = (f16)acc[mi][nt][r];
          }
      __syncthreads();
      f16* Kt = outH + (1 << 23);
#pragma unroll
      for (int u = 0; u < 8; ++u) {
        int sid = u * 256 + t;
        int wmt = sid >> 10, rem = sid & 1023;
        int nl = rem >> 3, a8 = rem & 7;
        int g = (rb >> 6) + wmt;
        int n = cbK + nl;
        int i = ((n & 7) << 6) | (n >> 3);
        *reinterpret_cast<f16x8*>(Kt + (long)g * 32768 + i * 64 + a8 * 8) =
            *reinterpret_cast<const f16x8*>(smem + wmt * 9216 + nl * 72 + a8 * 8);
      }
    } else {                             // V -> Vtg[a][i], via LDS retile
      int j = blockIdx.y - 8;
      __syncthreads();
#pragma unroll
      for (int mi = 0; mi < 4; ++mi)
#pragma unroll
        for (int nt = 0; nt < NT; ++nt)
#pragma unroll
          for (int r = 0; r < 4; ++r) {
            int a   = 16 * nt + lrow;
            int npl = 64 * wn + 16 * mi + 4 * lg + r;
            smem[wm * 8704 + a * 136 + npl] = (f16)acc[mi][nt][r];
          }
      __syncthreads();
      f16* Vt = outH + (2 << 23);
#pragma unroll
      for (int u = 0; u < 8; ++u) {
        int sid = u * 256 + t;
        int wmt = sid >> 10, rem = sid & 1023;
        int a = rem >> 4, n8 = rem & 15;
        int g = (rb >> 6) + wmt;
        *reinterpret_cast<f16x8*>(Vt + (long)g * 32768 + a * 512 + j * 128 + n8 * 8) =
            *reinterpret_cast<const f16x8*>(smem + wmt * 8704 + a * 136 + n8 * 8);
      }
    }
  }
}

// ---------------- flash attention: QBLK=256/block (2 blocks/group), dbuf async staging ----------------
// K LDS row p holds global key kappa(p) = 32(p>>5) + 8((p>>2)&3) + 4((p>>4)&1) + (p&3),
// so St[mi][nt][r] packs DIRECTLY into the PV A-fragment (in-register, no Psh).
// Each wave owns 64 query rows (mi<4); K/V staged 2x per group instead of 4x.
__global__ __launch_bounds__(256, 2) void k_attn(const f16* __restrict__ Qh,
                                                 const f16* __restrict__ Ktg,
                                                 const f16* __restrict__ Vtg,
                                                 f16* __restrict__ Of) {
  __shared__ f16 Ksh[2][64 * 64];
  __shared__ f16 Vsh[2][64 * 64];
  int u = blockIdx.x;
  int g = (u & 7) | ((u >> 4) << 3);   // both row-halves of a group share u&7 (same XCD slot)
  int mb = (u >> 3) & 1;
  int t = threadIdx.x, w = t >> 6, l = t & 63;
  int lrow = l & 15, lg = l >> 4, lk8 = lg * 8;
  long gp = (long)g * 32768;
  const f16* Qg = Qh + gp;
  const f16* Kg = Ktg + gp;
  const f16* Vg = Vtg + gp;
  f16* Og = Of + gp;
  int m0 = mb * 256 + w * 64;

  f16x8 qf[4][2];
#pragma unroll
  for (int mi = 0; mi < 4; ++mi)
#pragma unroll
    for (int ks = 0; ks < 2; ++ks)
      qf[mi][ks] = *reinterpret_cast<const f16x8*>(Qg + (long)(m0 + 16 * mi + lrow) * 64 + 32 * ks + lk8);

  // stage chunk c: K row p <- global key kappa(p) (pre-swizzled src, linear dest);
  // V identity. 2 K-DMA + 2 V-DMA per thread (16B each).
  auto stage = [&](int buf, int c) {
#pragma unroll
    for (int s = 0; s < 2; ++s) {
      int slot = s * 256 + t;
      int row = slot >> 3, pblk = slot & 7;
      int kr = 32 * (row >> 5) + 8 * ((row >> 2) & 3) + 4 * ((row >> 4) & 1) + (row & 3);
      gload16(Kg + (long)c * 4096 + kr * 64 + ((pblk ^ (row & 7)) * 8),
              Ksh[buf] + slot * 8);
    }
#pragma unroll
    for (int s = 0; s < 2; ++s) {
      int slot = s * 256 + t;
      int a = slot >> 3, pblk = slot & 7;
      gload16(Vg + (long)a * 512 + c * 64 + ((pblk ^ (a & 7)) * 8),
              Vsh[buf] + slot * 8);
    }
  };

  f32x4 accO[4][4] = {};
  float Mx[4] = {-INFINITY, -INFINITY, -INFINITY, -INFINITY};
  float Ls[4] = {0.f, 0.f, 0.f, 0.f};

  stage(0, 0);
  stage(1, 1);

  for (int c = 0; c < 8; ++c) {
    int buf = c & 1;
    if (c < 7) asm volatile("s_waitcnt vmcnt(4)" ::: "memory");
    else       asm volatile("s_waitcnt vmcnt(0)" ::: "memory");
    __builtin_amdgcn_s_barrier();

    // S^T = K . Q^T : A-frag from Ksh (swizzled b128, 2-way max).
    f32x4 St[4][4] = {};
    __builtin_amdgcn_s_setprio(1);
#pragma unroll
    for (int nt = 0; nt < 4; ++nt) {
      int n = 16 * nt + lrow, nb = n & 7;
      f16x8 ka = *reinterpret_cast<const f16x8*>(Ksh[buf] + n * 64 + ((lg ^ nb) * 8));
      f16x8 kb = *reinterpret_cast<const f16x8*>(Ksh[buf] + n * 64 + (((4 + lg) ^ nb) * 8));
#pragma unroll
      for (int mi = 0; mi < 4; ++mi) {
        St[mi][nt] = __builtin_amdgcn_mfma_f32_16x16x32_f16(ka, qf[mi][0], St[mi][nt], 0, 0, 0);
        St[mi][nt] = __builtin_amdgcn_mfma_f32_16x16x32_f16(kb, qf[mi][1], St[mi][nt], 0, 0, 0);
      }
    }
    __builtin_amdgcn_s_setprio(0);

    // wave-parallel online softmax (lane owns qrow = 16mi+lrow; keys split across lg)
    float scb[4][4];
#pragma unroll
    for (int mi = 0; mi < 4; ++mi) {
      float tm = St[mi][0][0];
#pragma unroll
      for (int nt = 0; nt < 4; ++nt)
#pragma unroll
        for (int r = 0; r < 4; ++r) tm = fmaxf(tm, St[mi][nt][r]);
      tm = fmaxf(tm, __shfl_xor(tm, 16));
      tm = fmaxf(tm, __shfl_xor(tm, 32));
      float nm = fmaxf(Mx[mi], tm);
      float sc = __expf(Mx[mi] - nm);   // chunk 0: exp(-inf)=0
      Mx[mi] = nm;
      float ps = 0.f;
#pragma unroll
      for (int nt = 0; nt < 4; ++nt)
#pragma unroll
        for (int r = 0; r < 4; ++r) {
          float p = __expf(St[mi][nt][r] - nm);
          St[mi][nt][r] = p;
          ps += p;
        }
      ps += __shfl_xor(ps, 16);
      ps += __shfl_xor(ps, 32);
      Ls[mi] = Ls[mi] * sc + ps;
#pragma unroll
      for (int r = 0; r < 4; ++r) scb[mi][r] = __shfl(sc, 20 * lg + r);
    }
#pragma unroll
    for (int mi = 0; mi < 4; ++mi)
#pragma unroll
      for (int at = 0; at < 4; ++at)
#pragma unroll
        for (int r = 0; r < 4; ++r) accO[mi][at][r] *= scb[mi][r];

    // O += P . V : A-frag packed IN-REGISTER from St; B-frag from Vsh (swizzled, 2-way max).
    __builtin_amdgcn_s_setprio(1);
#pragma unroll
    for (int ks = 0; ks < 2; ++ks) {
      f16x8 pa[4];
#pragma unroll
      for (int mi = 0; mi < 4; ++mi) {
        pa[mi][0] = (f16)St[mi][2 * ks][0];
        pa[mi][1] = (f16)St[mi][2 * ks][1];
        pa[mi][2] = (f16)St[mi][2 * ks][2];
        pa[mi][3] = (f16)St[mi][2 * ks][3];
        pa[mi][4] = (f16)St[mi][2 * ks + 1][0];
        pa[mi][5] = (f16)St[mi][2 * ks + 1][1];
        pa[mi][6] = (f16)St[mi][2 * ks + 1][2];
        pa[mi][7] = (f16)St[mi][2 * ks + 1][3];
      }
#pragma unroll
      for (int at = 0; at < 4; ++at) {
        int a = 16 * at + lrow, ab = a & 7;
        f16x8 vb = *reinterpret_cast<const f16x8*>(Vsh[buf] + a * 64 + (((4 * ks + lg) ^ ab) * 8));
#pragma unroll
        for (int mi = 0; mi < 4; ++mi)
          accO[mi][at] = __builtin_amdgcn_mfma_f32_16x16x32_f16(pa[mi], vb, accO[mi][at], 0, 0, 0);
      }
    }
    __builtin_amdgcn_s_setprio(0);

    __builtin_amdgcn_s_barrier();
    if (c + 2 < 8) stage(buf, c + 2);
  }

  // epilogue: redistribute 1/L, normalize, store f16
#pragma unroll
  for (int mi = 0; mi < 4; ++mi) {
    float inv = 1.f / Ls[mi];
    float invb[4];
#pragma unroll
    for (int r = 0; r < 4; ++r) invb[r] = __shfl(inv, 20 * lg + r);
#pragma unroll
    for (int r = 0; r < 4; ++r) {
      int row = m0 + 16 * mi + 4 * lg + r;
#pragma unroll
      for (int at = 0; at < 4; ++at)
        Og[(long)row * 64 + 16 * at + lrow] = (f16)(accO[mi][at][r] * invb[r]);
    }
  }
}

// ---------------- finalize: head-mean + R + relu ----------------
__global__ __launch_bounds__(256) void k_finalize(const f16* __restrict__ Of,
                                                  const float* __restrict__ Rf,
                                                  float* __restrict__ out) {
  int i = blockIdx.x * 256 + threadIdx.x;
  f32x4 s = {};
#pragma unroll
  for (int h = 0; h < 8; ++h) {
    f16x4 o = reinterpret_cast<const f16x4*>(Of + (long)h * 1048576)[i];
#pragma unroll
    for (int j = 0; j < 4; ++j) s[j] += (float)o[j];
  }
  f32x4 r = reinterpret_cast<const f32x4*>(Rf)[i];
  f32x4 v = s * 0.125f + r;
#pragma unroll
  for (int j = 0; j < 4; ++j) v[j] = v[j] > 0.f ? v[j] : 0.f;
  reinterpret_cast<f32x4*>(out)[i] = v;
}

extern "C" void kernel_launch(void* const* d_in, const int* in_sizes, int n_in,
                              void* d_out, int out_size, void* d_ws, size_t ws_size,
                              hipStream_t stream) {
  const float* x  = (const float*)d_in[0];
  const float* Wq = (const float*)d_in[1];
  const float* Wk = (const float*)d_in[2];
  const float* Wv = (const float*)d_in[3];
  const float* Wr = (const float*)d_in[4];
  float* out = (float*)d_out;
  char* w = (char*)d_ws;

  // workspace layout (bytes), ~80.5 MiB total:
  f16*   Xh   = (f16*)(w + 0);           // 8,388,608
  f16*   Wt   = (f16*)(w + 8388608);     // 786,432
  f16*   Wrt  = (f16*)(w + 9175040);     // 32,768
  f16*   Qh   = (f16*)(w + 9207808);     // Q|Ktg|Vtg contiguous, 3 x 16,777,216 (2^23 f16 apart)
  f16*   Ktg  = (f16*)(w + 25985024);
  f16*   Vtg  = (f16*)(w + 42762240);
  float* Rf   = (float*)(w + 59539456);  // 4,194,304
  f16*   Of   = (f16*)(w + 63733760);    // 16,777,216

  k_cast<<<4096, 256, 0, stream>>>(x, Xh, 1048576);
  k_transpose_w<<<100, 256, 0, stream>>>(Wq, Wk, Wv, Wr, Wt, Wrt);

  k_gemm<128, false><<<dim3(128, 12), 256, 0, stream>>>(Xh, Wt, Qh, nullptr, 512);
  k_gemm<64, true><<<dim3(128, 1), 256, 0, stream>>>(Xh, Wrt, nullptr, Rf, 64);

  k_attn<<<512, 256, 0, stream>>>(Qh, Ktg, Vtg, Of);
  k_finalize<<<1024, 256, 0, stream>>>(Of, Rf, out);
}